// Round 10
// baseline (636.222 us; speedup 1.0000x reference)
//
#include <hip/hip_runtime.h>

#define Tsz 512
#define Hsz 256

typedef __attribute__((ext_vector_type(8))) short short8;
typedef __attribute__((ext_vector_type(4))) short short4v;
typedef __attribute__((ext_vector_type(4))) float f32x4;

static __device__ __forceinline__ unsigned short f2bf(float f) {
    union { float f; unsigned int i; } v; v.f = f;
    unsigned int r = v.i + 0x7fffu + ((v.i >> 16) & 1u);   // RNE
    return (unsigned short)(r >> 16);
}
static __device__ __forceinline__ short8 ld8f(const float* p) {
    const float4* q = (const float4*)p;
    float4 a = q[0], b = q[1];
    short8 v;
    v[0] = (short)f2bf(a.x); v[1] = (short)f2bf(a.y); v[2] = (short)f2bf(a.z); v[3] = (short)f2bf(a.w);
    v[4] = (short)f2bf(b.x); v[5] = (short)f2bf(b.y); v[6] = (short)f2bf(b.z); v[7] = (short)f2bf(b.w);
    return v;
}
static __device__ __forceinline__ float sigm(float z) {
    return __builtin_amdgcn_rcpf(1.f + __expf(-z));
}

// Pre-kernel: Wx f32 -> bf16 row-major in d_ws (one 16B frag load per drip MFMA)
__global__ __launch_bounds__(256) void cvt_wx(const float* __restrict__ Wxw,
                                              unsigned short* __restrict__ wxbf)
{
    int i = (blockIdx.x * 256 + threadIdx.x) * 4;
    float4 v = *(const float4*)(Wxw + i);
    short4v s4;
    s4[0] = (short)f2bf(v.x); s4[1] = (short)f2bf(v.y);
    s4[2] = (short)f2bf(v.z); s4[3] = (short)f2bf(v.w);
    *(short4v*)(wxbf + i) = s4;
}

// Fused MGU, ROLE-SPLIT: 12 waves (768 thr), 1 block/CU, 1 batch/block.
// Waves 0-7 scan-only (N=32 each, Wh resident = 64 VGPR). Waves 8-11 helpers:
// gate GEMM drip (N=64 each, Wx frags streamed bf16 from d_ws), x staging,
// gate epilogue. 12 waves = 3/SIMD -> ~170-VGPR cap; scan live ~130, helper ~60.
__global__ __launch_bounds__(768, 1) void mgu_fused(
    const float* __restrict__ x,   const unsigned short* __restrict__ wxbf,
    const float* __restrict__ Wxb, const float* __restrict__ Whw,
    const float* __restrict__ Whb, float* __restrict__ out)
{
    __shared__ __align__(16) unsigned short xs[2][16 * 256];  // bf16 x chunks, swizzled
    __shared__ __align__(16) float          gs[2][16 * 256];  // f32 gates
    __shared__ __align__(16) unsigned short hbuf[2][256];     // bf16 h double buffer

    const int tid  = threadIdx.x;
    const int b    = blockIdx.x;
    const int l    = tid & 63;
    const int w    = tid >> 6;        // 0..11
    const int lo16 = l & 15;
    const int hi   = l >> 4;
    const bool is_scan = (w < 8);
    const int hw   = w - 8;           // helper index 0..3

    const float* xrow = x   + (size_t)b * Tsz * Hsz;
    float*       orow = out + (size_t)b * Tsz * Hsz;

    // ---- per-role persistent state ----
    // scan: Wh B-frags resident. B[k][n]=Wh[n][k]; lane n=w*32+nt*16+lo16, k=ks*32+hi*8..
    short8 wfh[2][8];
    float  bh0 = 0.f, bh1 = 0.f;
    // helper: gate stream base + biases
    const unsigned short* gwb = wxbf + (size_t)(hw * 64 + lo16) * 256 + hi * 8;
    float bxv[4];
    if (is_scan) {
#pragma unroll
        for (int nt = 0; nt < 2; ++nt) {
            int n = w * 32 + nt * 16 + lo16;
#pragma unroll
            for (int ks = 0; ks < 8; ++ks)
                wfh[nt][ks] = ld8f(Whw + (size_t)n * 256 + ks * 32 + hi * 8);
        }
        bh0 = Whb[w * 32 + lo16]; bh1 = Whb[w * 32 + 16 + lo16];
    } else {
#pragma unroll
        for (int ntl = 0; ntl < 4; ++ntl)
            bxv[ntl] = Wxb[hw * 64 + ntl * 16 + lo16];
    }

    // staging: helper waves, lanes 0..15 -> lq 0..63 (1KB/step, 8B LDS writes)
    const bool stg = (!is_scan) && (l < 16);
    const int  lq  = hw * 16 + (l & 15);
    const int  qh  = lq >> 1, q1 = lq & 1;

    // ---- prologue: stage x chunks 0,1 (bf16, 16B-chunk XOR swizzle) ----
    for (int idx = tid; idx < 2048; idx += 768) {
        int m = idx >> 6;
        int j = idx & 63;
        float4 v = *(const float4*)(xrow + (size_t)m * 256 + j * 4);
        short4v s4;
        s4[0] = (short)f2bf(v.x); s4[1] = (short)f2bf(v.y);
        s4[2] = (short)f2bf(v.z); s4[3] = (short)f2bf(v.w);
        int r   = m & 15;
        int byt = r * 512 + (((j >> 1) ^ (r & 7)) << 4) + (j & 1) * 8;
        *(short4v*)((char*)xs[m >> 4] + byt) = s4;
    }
    if (tid < 256) hbuf[0][tid] = 0;
    __syncthreads();

    // ---- gates chunk 0 (helpers, full pass: 32 MFMAs each) ----
    if (!is_scan) {
        f32x4 ag[4];
#pragma unroll
        for (int ntl = 0; ntl < 4; ++ntl) { f32x4 z = {0.f, 0.f, 0.f, 0.f}; ag[ntl] = z; }
#pragma unroll
        for (int ks = 0; ks < 8; ++ks) {
            short8 a = *(const short8*)((const char*)xs[0]
                         + lo16 * 512 + (((ks * 4 + hi) ^ (lo16 & 7)) << 4));
#pragma unroll
            for (int ntl = 0; ntl < 4; ++ntl) {
                short8 bf = *(const short8*)(gwb + (size_t)(ntl * 16) * 256 + ks * 32);
                ag[ntl] = __builtin_amdgcn_mfma_f32_16x16x32_bf16(a, bf, ag[ntl], 0, 0, 0);
            }
        }
#pragma unroll
        for (int ntl = 0; ntl < 4; ++ntl)
#pragma unroll
            for (int r = 0; r < 4; ++r)
                gs[0][(hi * 4 + r) * 256 + hw * 64 + ntl * 16 + lo16] = sigm(ag[ntl][r] + bxv[ntl]);
    }

    float  hreg = 0.f;
    float4 xcarry;
    if (stg) xcarry = *(const float4*)(xrow + (size_t)32 * 256 + lq * 4);

    f32x4 accg[4];
#pragma unroll
    for (int ntl = 0; ntl < 4; ++ntl) { f32x4 z = {0.f, 0.f, 0.f, 0.f}; accg[ntl] = z; }
    short8 afg;

    int p = 0;
    for (int c = 0; c < 32; ++c) {
        const char*  xs_rd = (const char*)xs[(c & 1) ^ 1];
        char*        xs_wr = (char*)xs[c & 1];
        const float* gs_rd = gs[c & 1];
        float*       gs_wr = gs[(c & 1) ^ 1];
#pragma unroll
        for (int s = 0; s < 16; ++s) {
            const int t = c * 16 + s;
            __syncthreads();                    // single barrier point, all 12 waves

            if (is_scan) {
                const int n_ep = w * 32 + (hi & 1) * 16 + lo16;
                float g = gs_rd[s * 256 + n_ep];

                short8 afh[8];
#pragma unroll
                for (int ks = 0; ks < 8; ++ks)
                    afh[ks] = *(const short8*)(const void*)(&hbuf[p][ks * 32 + hi * 8]);

                f32x4 a0lo = {bh0, 0.f, 0.f, 0.f}, a0hi = {0.f, 0.f, 0.f, 0.f};
                f32x4 a1lo = {bh1, 0.f, 0.f, 0.f}, a1hi = {0.f, 0.f, 0.f, 0.f};
                __builtin_amdgcn_s_setprio(1);
#pragma unroll
                for (int ks = 0; ks < 4; ++ks) {
                    a0lo = __builtin_amdgcn_mfma_f32_16x16x32_bf16(afh[ks],     wfh[0][ks],     a0lo, 0, 0, 0);
                    a1lo = __builtin_amdgcn_mfma_f32_16x16x32_bf16(afh[ks],     wfh[1][ks],     a1lo, 0, 0, 0);
                    a0hi = __builtin_amdgcn_mfma_f32_16x16x32_bf16(afh[ks + 4], wfh[0][ks + 4], a0hi, 0, 0, 0);
                    a1hi = __builtin_amdgcn_mfma_f32_16x16x32_bf16(afh[ks + 4], wfh[1][ks + 4], a1hi, 0, 0, 0);
                }
                __builtin_amdgcn_s_setprio(0);

                float zz = (hi == 0) ? (a0lo[0] + a0hi[0]) : (a1lo[0] + a1hi[0]);
                zz = fminf(fmaxf(zz, -15.f), 15.f);
                float ex = __expf(2.f * zz);
                float th = (ex - 1.f) * __builtin_amdgcn_rcpf(ex + 1.f);
                if (hi < 2) {
                    float hn = g * hreg + (1.f - g) * th;
                    hreg = hn;
                    hbuf[p ^ 1][n_ep] = f2bf(hn);
                    orow[(size_t)t * 256 + n_ep] = hn;
                }
            } else {
                // gate drip: MFMA m0=2s, m1=2s+1 of 32 (ntl=m&3, ks=m>>2)
                if ((s & 1) == 0)
                    afg = *(const short8*)(xs_rd
                            + lo16 * 512 + ((((s >> 1) * 4 + hi) ^ (lo16 & 7)) << 4));
                {
                    const int m0 = 2 * s, m1 = 2 * s + 1;
                    short8 bf0 = *(const short8*)(gwb + (size_t)((m0 & 3) * 16) * 256 + (m0 >> 2) * 32);
                    short8 bf1 = *(const short8*)(gwb + (size_t)((m1 & 3) * 16) * 256 + (m1 >> 2) * 32);
                    accg[m0 & 3] = __builtin_amdgcn_mfma_f32_16x16x32_bf16(afg, bf0, accg[m0 & 3], 0, 0, 0);
                    accg[m1 & 3] = __builtin_amdgcn_mfma_f32_16x16x32_bf16(afg, bf1, accg[m1 & 3], 0, 0, 0);
                }

                if (stg) {   // stage x row t+32 (chunk c+2, row s)
                    short4v s4;
                    s4[0] = (short)f2bf(xcarry.x); s4[1] = (short)f2bf(xcarry.y);
                    s4[2] = (short)f2bf(xcarry.z); s4[3] = (short)f2bf(xcarry.w);
                    *(short4v*)(xs_wr + s * 512 + ((qh ^ (s & 7)) << 4) + q1 * 8) = s4;
                    int nr = t + 33; if (nr > Tsz - 1) nr = Tsz - 1;
                    xcarry = *(const float4*)(xrow + (size_t)nr * 256 + lq * 4);
                }

                if (s == 15) {   // finish gates chunk c+1
#pragma unroll
                    for (int ntl = 0; ntl < 4; ++ntl) {
#pragma unroll
                        for (int r = 0; r < 4; ++r)
                            gs_wr[(hi * 4 + r) * 256 + hw * 64 + ntl * 16 + lo16]
                                = sigm(accg[ntl][r] + bxv[ntl]);
                        f32x4 z = {0.f, 0.f, 0.f, 0.f}; accg[ntl] = z;
                    }
                }
            }
            p ^= 1;
        }
    }
}

extern "C" void kernel_launch(void* const* d_in, const int* in_sizes, int n_in,
                              void* d_out, int out_size, void* d_ws, size_t ws_size,
                              hipStream_t stream) {
    const float* x   = (const float*)d_in[0];
    const float* Wxw = (const float*)d_in[1];
    const float* Wxb = (const float*)d_in[2];
    const float* Whw = (const float*)d_in[3];
    const float* Whb = (const float*)d_in[4];
    unsigned short* wxbf = (unsigned short*)d_ws;   // 128 KiB bf16 Wx

    cvt_wx<<<dim3(64), dim3(256), 0, stream>>>(Wxw, wxbf);
    mgu_fused<<<dim3(256), dim3(768), 0, stream>>>(x, wxbf, Wxb, Whw, Whb, (float*)d_out);
}

// Round 11
// 277.667 us; speedup vs baseline: 2.2913x; 2.2913x over previous
//
#include <hip/hip_runtime.h>

#define Tsz 512
#define Hsz 256

typedef __attribute__((ext_vector_type(8))) short short8;
typedef __attribute__((ext_vector_type(4))) short short4v;
typedef __attribute__((ext_vector_type(4))) float f32x4;

static __device__ __forceinline__ unsigned short f2bf(float f) {
    union { float f; unsigned int i; } v; v.f = f;
    unsigned int r = v.i + 0x7fffu + ((v.i >> 16) & 1u);   // RNE
    return (unsigned short)(r >> 16);
}
static __device__ __forceinline__ short8 ld8f(const float* p) {
    const float4* q = (const float4*)p;
    float4 a = q[0], b = q[1];
    short8 v;
    v[0] = (short)f2bf(a.x); v[1] = (short)f2bf(a.y); v[2] = (short)f2bf(a.z); v[3] = (short)f2bf(a.w);
    v[4] = (short)f2bf(b.x); v[5] = (short)f2bf(b.y); v[6] = (short)f2bf(b.z); v[7] = (short)f2bf(b.w);
    return v;
}
static __device__ __forceinline__ float sigm(float z) {
    return __builtin_amdgcn_rcpf(1.f + __expf(-z));
}

// Pre-kernel: Wx f32 -> bf16 row-major in d_ws (one 16B load per drip B-frag)
__global__ __launch_bounds__(256) void cvt_wx(const float* __restrict__ Wxw,
                                              unsigned short* __restrict__ wxbf)
{
    int i = (blockIdx.x * 256 + threadIdx.x) * 4;
    float4 v = *(const float4*)(Wxw + i);
    short4v s4;
    s4[0] = (short)f2bf(v.x); s4[1] = (short)f2bf(v.y);
    s4[2] = (short)f2bf(v.z); s4[3] = (short)f2bf(v.w);
    *(short4v*)(wxbf + i) = s4;
}

// Fused MGU, 8 waves/block, 1 block/CU (grid=256). Wave w owns cols [w*32,w*32+32).
// Wh resident (64 VGPR). Wx drip B-frag = ONE 16B L2 load per step from the
// pre-converted bf16 copy in d_ws, issued post-barrier and consumed ~600cy
// later (L2 latency hidden) — removes the resident wfx that caused the
// structural 28MB/dispatch spill (allocator hard-caps 8-wave blocks at 128).
__global__ __launch_bounds__(512, 2) void mgu_fused(
    const float* __restrict__ x,   const unsigned short* __restrict__ wxbf,
    const float* __restrict__ Wxb, const float* __restrict__ Whw,
    const float* __restrict__ Whb, float* __restrict__ out)
{
    __shared__ __align__(16) unsigned short xs[2][16 * 256];  // bf16 x chunks, swizzled
    __shared__ __align__(16) float          gs[2][16 * 256];  // f32 gates
    __shared__ __align__(16) unsigned short hbuf[2][256];     // bf16 h double buffer

    const int tid  = threadIdx.x;
    const int b    = blockIdx.x;
    const int l    = tid & 63;
    const int w    = tid >> 6;       // 0..7
    const int lo16 = l & 15;
    const int hi   = l >> 4;

    // Wh B-frags resident: B[k][n]=Wh[n][k]; lane n=w*32+nt*16+lo16, k=ks*32+hi*8..+7
    short8 wfh[2][8];
    float  bh[2], bx[2];
#pragma unroll
    for (int nt = 0; nt < 2; ++nt) {
        int n = w * 32 + nt * 16 + lo16;
        bh[nt] = Whb[n];
        bx[nt] = Wxb[n];
#pragma unroll
        for (int ks = 0; ks < 8; ++ks)
            wfh[nt][ks] = ld8f(Whw + (size_t)n * 256 + ks * 32 + hi * 8);
    }

    // gate B-frag stream base (bf16, row-major): frag(nt,ks) at +nt*16*256 + ks*32
    const unsigned short* gwb = wxbf + (size_t)(w * 32 + lo16) * 256 + hi * 8;

    const float* xrow = x   + (size_t)b * Tsz * Hsz;
    float*       orow = out + (size_t)b * Tsz * Hsz;

    // ---- prologue: stage x chunks 0,1 (bf16, 16B-chunk XOR swizzle) ----
#pragma unroll
    for (int i = 0; i < 4; ++i) {
        int idx = tid + i * 512;          // 0..2047
        int m   = idx >> 6;               // global row 0..31
        int j   = idx & 63;               // float4 index in row
        float4 v = *(const float4*)(xrow + (size_t)m * 256 + j * 4);
        short4v s4;
        s4[0] = (short)f2bf(v.x); s4[1] = (short)f2bf(v.y);
        s4[2] = (short)f2bf(v.z); s4[3] = (short)f2bf(v.w);
        int r   = m & 15;
        int byt = r * 512 + (((j >> 1) ^ (r & 7)) << 4) + (j & 1) * 8;
        *(short4v*)((char*)xs[m >> 4] + byt) = s4;
    }
    if (tid < 256) hbuf[0][tid] = 0;
    __syncthreads();

    // ---- gates chunk 0 (full pass: 16 MFMAs/wave, streamed B-frags) ----
    {
        f32x4 ag0 = {0.f, 0.f, 0.f, 0.f}, ag1 = {0.f, 0.f, 0.f, 0.f};
#pragma unroll
        for (int ks = 0; ks < 8; ++ks) {
            short8 afg = *(const short8*)((const char*)xs[0]
                           + lo16 * 512 + (((ks * 4 + hi) ^ (lo16 & 7)) << 4));
            short8 b0 = *(const short8*)(gwb + ks * 32);
            short8 b1 = *(const short8*)(gwb + 16 * 256 + ks * 32);
            ag0 = __builtin_amdgcn_mfma_f32_16x16x32_bf16(afg, b0, ag0, 0, 0, 0);
            ag1 = __builtin_amdgcn_mfma_f32_16x16x32_bf16(afg, b1, ag1, 0, 0, 0);
        }
#pragma unroll
        for (int r = 0; r < 4; ++r) {
            gs[0][(hi * 4 + r) * 256 + w * 32 + lo16]      = sigm(ag0[r] + bx[0]);
            gs[0][(hi * 4 + r) * 256 + w * 32 + 16 + lo16] = sigm(ag1[r] + bx[1]);
        }
    }

    float  hreg = 0.f;
    float4 xcarry;
    if (tid < 64) xcarry = *(const float4*)(xrow + (size_t)32 * 256 + tid * 4);

    f32x4 accg[2];
    { f32x4 z = {0.f, 0.f, 0.f, 0.f}; accg[0] = z; accg[1] = z; }

    int p = 0;
    for (int c = 0; c < 32; ++c) {
        const char*  xs_rd = (const char*)xs[(c & 1) ^ 1];  // x of chunk c+1 (drip source)
        char*        xs_wr = (char*)xs[c & 1];              // staging x of chunk c+2
        const float* gs_rd = gs[c & 1];                     // gates of chunk c
        float*       gs_wr = gs[(c & 1) ^ 1];               // gates of chunk c+1
        short8 afg;
#pragma unroll
        for (int s = 0; s < 16; ++s) {
            const int t = c * 16 + s;
            __syncthreads();                    // h[t-1], gates, staged x visible

            // gate B-frag (nt=s&1, ks=s>>1): issue L2 load NOW, use ~600cy later
            short8 gbf = *(const short8*)(gwb + (s & 1) * (16 * 256) + (s >> 1) * 32);

            // hoist gate read (independent of h) off the critical tail
            const int n_ep = w * 32 + (hi & 1) * 16 + lo16;   // used by hi<2
            float g = gs_rd[s * 256 + n_ep];

            // drip A-frag early (even s): ds_read hides under h-MFMAs
            if ((s & 1) == 0)
                afg = *(const short8*)(xs_rd
                        + lo16 * 512 + ((((s >> 1) * 4 + hi) ^ (lo16 & 7)) << 4));

            // h-matvec in two halves (afh liveness 16 regs, 4 indep chains)
            f32x4 a0lo = {bh[0], 0.f, 0.f, 0.f}, a0hi = {0.f, 0.f, 0.f, 0.f};
            f32x4 a1lo = {bh[1], 0.f, 0.f, 0.f}, a1hi = {0.f, 0.f, 0.f, 0.f};
            {
                short8 afh[4];
#pragma unroll
                for (int ks = 0; ks < 4; ++ks)
                    afh[ks] = *(const short8*)(const void*)(&hbuf[p][ks * 32 + hi * 8]);
#pragma unroll
                for (int ks = 0; ks < 4; ++ks) {
                    a0lo = __builtin_amdgcn_mfma_f32_16x16x32_bf16(afh[ks], wfh[0][ks], a0lo, 0, 0, 0);
                    a1lo = __builtin_amdgcn_mfma_f32_16x16x32_bf16(afh[ks], wfh[1][ks], a1lo, 0, 0, 0);
                }
            }
            {
                short8 afh[4];
#pragma unroll
                for (int ks = 0; ks < 4; ++ks)
                    afh[ks] = *(const short8*)(const void*)(&hbuf[p][(ks + 4) * 32 + hi * 8]);
#pragma unroll
                for (int ks = 0; ks < 4; ++ks) {
                    a0hi = __builtin_amdgcn_mfma_f32_16x16x32_bf16(afh[ks], wfh[0][ks + 4], a0hi, 0, 0, 0);
                    a1hi = __builtin_amdgcn_mfma_f32_16x16x32_bf16(afh[ks], wfh[1][ks + 4], a1hi, 0, 0, 0);
                }
            }

            // gate drip: 1 MFMA/step with the streamed B-frag
            accg[s & 1] = __builtin_amdgcn_mfma_f32_16x16x32_bf16(afg, gbf, accg[s & 1], 0, 0, 0);

            // stage x row t+32 (chunk c+2, row s): wave 0, 8B writes
            if (tid < 64) {
                short4v s4;
                s4[0] = (short)f2bf(xcarry.x); s4[1] = (short)f2bf(xcarry.y);
                s4[2] = (short)f2bf(xcarry.z); s4[3] = (short)f2bf(xcarry.w);
                int byt = s * 512 + (((tid >> 1) ^ (s & 7)) << 4) + (tid & 1) * 8;
                *(short4v*)(xs_wr + byt) = s4;
                int nr = t + 33; if (nr > Tsz - 1) nr = Tsz - 1;
                xcarry = *(const float4*)(xrow + (size_t)nr * 256 + tid * 4);
            }

            // epilogue: col n = w*32 + hi*16 + lo16 owned by hi<2 threads
            float zz = (hi == 0) ? (a0lo[0] + a0hi[0]) : (a1lo[0] + a1hi[0]);
            zz = fminf(fmaxf(zz, -15.f), 15.f);
            float ex = __expf(2.f * zz);
            float th = (ex - 1.f) * __builtin_amdgcn_rcpf(ex + 1.f);
            if (hi < 2) {
                float hn = g * hreg + (1.f - g) * th;
                hreg = hn;
                hbuf[p ^ 1][n_ep] = f2bf(hn);
                orow[(size_t)t * 256 + n_ep] = hn;
            }

            if (s == 15) {   // finish gates chunk c+1
#pragma unroll
                for (int r = 0; r < 4; ++r) {
                    gs_wr[(hi * 4 + r) * 256 + w * 32 + lo16]      = sigm(accg[0][r] + bx[0]);
                    gs_wr[(hi * 4 + r) * 256 + w * 32 + 16 + lo16] = sigm(accg[1][r] + bx[1]);
                }
                f32x4 z = {0.f, 0.f, 0.f, 0.f}; accg[0] = z; accg[1] = z;
            }
            p ^= 1;
        }
    }
}

extern "C" void kernel_launch(void* const* d_in, const int* in_sizes, int n_in,
                              void* d_out, int out_size, void* d_ws, size_t ws_size,
                              hipStream_t stream) {
    const float* x   = (const float*)d_in[0];
    const float* Wxw = (const float*)d_in[1];
    const float* Wxb = (const float*)d_in[2];
    const float* Whw = (const float*)d_in[3];
    const float* Whb = (const float*)d_in[4];
    unsigned short* wxbf = (unsigned short*)d_ws;   // 128 KiB bf16 Wx

    cvt_wx<<<dim3(64), dim3(256), 0, stream>>>(Wxw, wxbf);
    mgu_fused<<<dim3(256), dim3(512), 0, stream>>>(x, wxbf, Wxb, Whw, Whb, (float*)d_out);
}

// Round 12
// 237.835 us; speedup vs baseline: 2.6751x; 1.1675x over previous
//
#include <hip/hip_runtime.h>

#define Tsz 512
#define Hsz 256

typedef __attribute__((ext_vector_type(8))) short short8;
typedef __attribute__((ext_vector_type(4))) short short4v;
typedef __attribute__((ext_vector_type(4))) float f32x4;

static __device__ __forceinline__ unsigned short f2bf(float f) {
    union { float f; unsigned int i; } v; v.f = f;
    unsigned int r = v.i + 0x7fffu + ((v.i >> 16) & 1u);   // RNE
    return (unsigned short)(r >> 16);
}
static __device__ __forceinline__ float bf2f(unsigned short u) {
    union { unsigned int i; float f; } v; v.i = ((unsigned int)u) << 16; return v.f;
}
static __device__ __forceinline__ short8 ld8f(const float* p) {
    const float4* q = (const float4*)p;
    float4 a = q[0], b = q[1];
    short8 v;
    v[0] = (short)f2bf(a.x); v[1] = (short)f2bf(a.y); v[2] = (short)f2bf(a.z); v[3] = (short)f2bf(a.w);
    v[4] = (short)f2bf(b.x); v[5] = (short)f2bf(b.y); v[6] = (short)f2bf(b.z); v[7] = (short)f2bf(b.w);
    return v;
}
static __device__ __forceinline__ float sigm(float z) {
    return __builtin_amdgcn_rcpf(1.f + __expf(-z));
}

// Pre-kernel: Wx f32 -> bf16 row-major in d_ws (one 16B load per drip B-frag)
__global__ __launch_bounds__(256) void cvt_wx(const float* __restrict__ Wxw,
                                              unsigned short* __restrict__ wxbf)
{
    int i = (blockIdx.x * 256 + threadIdx.x) * 4;
    float4 v = *(const float4*)(Wxw + i);
    short4v s4;
    s4[0] = (short)f2bf(v.x); s4[1] = (short)f2bf(v.y);
    s4[2] = (short)f2bf(v.z); s4[3] = (short)f2bf(v.w);
    *(short4v*)(wxbf + i) = s4;
}

// Fused MGU, 8 waves/block, 1 block/CU (grid=256). Wave w owns cols [w*32,w*32+32).
// Wh resident; Wx drip B-frag streamed from d_ws (r11, proven). New in r12:
//  - bulk x staging spread over ALL 512 threads, 2 load/2 write steps per chunk
//    (kills the wave-0 per-step straggler; xs[c&1] is dead storage during chunk c)
//  - gate g prefetched one step ahead (gs stable within a chunk)
//  - gs stored bf16; xs rows padded to 264 ushorts (both sides ~conflict-free)
#define XP 264   // xs row stride (ushorts): 528B -> rows spread 8 bank-groups
__global__ __launch_bounds__(512, 2) void mgu_fused(
    const float* __restrict__ x,   const unsigned short* __restrict__ wxbf,
    const float* __restrict__ Wxb, const float* __restrict__ Whw,
    const float* __restrict__ Whb, float* __restrict__ out)
{
    __shared__ __align__(16) unsigned short xs[2][16 * XP];   // bf16 x chunks (~16.9KB)
    __shared__ __align__(16) unsigned short gsb[2][16 * 256]; // bf16 gates (16KB)
    __shared__ __align__(16) unsigned short hbuf[2][256];     // bf16 h double buffer

    const int tid  = threadIdx.x;
    const int b    = blockIdx.x;
    const int l    = tid & 63;
    const int w    = tid >> 6;       // 0..7
    const int lo16 = l & 15;
    const int hi   = l >> 4;
    const int n_ep = w * 32 + (hi & 1) * 16 + lo16;   // epilogue column (hi<2 own it)

    // Wh B-frags resident: B[k][n]=Wh[n][k]; lane n=w*32+nt*16+lo16, k=ks*32+hi*8..+7
    short8 wfh[2][8];
    float  bh[2], bx[2];
#pragma unroll
    for (int nt = 0; nt < 2; ++nt) {
        int n = w * 32 + nt * 16 + lo16;
        bh[nt] = Whb[n];
        bx[nt] = Wxb[n];
#pragma unroll
        for (int ks = 0; ks < 8; ++ks)
            wfh[nt][ks] = ld8f(Whw + (size_t)n * 256 + ks * 32 + hi * 8);
    }

    // gate B-frag stream base (bf16 row-major in d_ws)
    const unsigned short* gwb = wxbf + (size_t)(w * 32 + lo16) * 256 + hi * 8;

    const float* xrow = x   + (size_t)b * Tsz * Hsz;
    float*       orow = out + (size_t)b * Tsz * Hsz;

    // bulk-staging thread map: thread -> (row 0..7, float4-group 0..63)
    const int srow = tid >> 6;
    const int sj   = tid & 63;

    // ---- prologue: stage x chunks 0,1 ----
#pragma unroll
    for (int i = 0; i < 4; ++i) {
        int idx = tid + i * 512;          // 0..2047
        int m   = idx >> 6;               // global row 0..31
        int j   = idx & 63;
        float4 v = *(const float4*)(xrow + (size_t)m * 256 + j * 4);
        short4v s4;
        s4[0] = (short)f2bf(v.x); s4[1] = (short)f2bf(v.y);
        s4[2] = (short)f2bf(v.z); s4[3] = (short)f2bf(v.w);
        *(short4v*)(&xs[m >> 4][(m & 15) * XP + j * 4]) = s4;
    }
    if (tid < 256) hbuf[0][tid] = 0;
    __syncthreads();

    // ---- gates chunk 0 (full pass: 16 MFMAs/wave, streamed B-frags) ----
    {
        f32x4 ag0 = {0.f, 0.f, 0.f, 0.f}, ag1 = {0.f, 0.f, 0.f, 0.f};
#pragma unroll
        for (int ks = 0; ks < 8; ++ks) {
            short8 afg = *(const short8*)(&xs[0][lo16 * XP + ks * 32 + hi * 8]);
            short8 b0 = *(const short8*)(gwb + ks * 32);
            short8 b1 = *(const short8*)(gwb + 16 * 256 + ks * 32);
            ag0 = __builtin_amdgcn_mfma_f32_16x16x32_bf16(afg, b0, ag0, 0, 0, 0);
            ag1 = __builtin_amdgcn_mfma_f32_16x16x32_bf16(afg, b1, ag1, 0, 0, 0);
        }
#pragma unroll
        for (int r = 0; r < 4; ++r) {
            gsb[0][(hi * 4 + r) * 256 + w * 32 + lo16]      = f2bf(sigm(ag0[r] + bx[0]));
            gsb[0][(hi * 4 + r) * 256 + w * 32 + 16 + lo16] = f2bf(sigm(ag1[r] + bx[1]));
        }
    }

    float  hreg = 0.f;
    float  g_carry = 0.f;
    float4 stg;
    f32x4 accg[2];
    { f32x4 z = {0.f, 0.f, 0.f, 0.f}; accg[0] = z; accg[1] = z; }
    short8 afg;

    for (int c = 0; c < 32; ++c) {
        unsigned short*       xs_rd = xs[(c & 1) ^ 1];   // chunk c+1 (drip source)
        unsigned short*       xs_wr = xs[c & 1];         // dead -> stage chunk c+2
        const unsigned short* gs_rd = gsb[c & 1];        // gates of chunk c (stable)
        unsigned short*       gs_wr = gsb[(c & 1) ^ 1];  // gates of chunk c+1
#pragma unroll
        for (int s = 0; s < 16; ++s) {
            const int pp = s & 1;               // hbuf parity (compile-time)
            const int t  = c * 16 + s;
            __syncthreads();                    // h[t-1], gates, staged x visible

            // gate for this step: prefetched last step (gs stable within chunk)
            float g = (s == 0) ? bf2f(gs_rd[n_ep]) : g_carry;
            if (s < 15) g_carry = bf2f(gs_rd[(s + 1) * 256 + n_ep]);

            // gate B-frag: L2 load issued now, consumed at drip MFMA later
            short8 gbf = *(const short8*)(gwb + pp * (16 * 256) + (s >> 1) * 32);

            // drip A-frag (even s): one b128 from padded xs
            if ((s & 1) == 0)
                afg = *(const short8*)(&xs_rd[lo16 * XP + (s >> 1) * 32 + hi * 8]);

            // bulk staging of chunk c+2 (all threads, amortized)
            if (c < 30) {
                if (s == 0)
                    stg = *(const float4*)(xrow + (size_t)((c + 2) * 16 + srow) * 256 + sj * 4);
                if (s == 4) {
                    short4v s4;
                    s4[0] = (short)f2bf(stg.x); s4[1] = (short)f2bf(stg.y);
                    s4[2] = (short)f2bf(stg.z); s4[3] = (short)f2bf(stg.w);
                    *(short4v*)(&xs_wr[srow * XP + sj * 4]) = s4;
                }
                if (s == 8)
                    stg = *(const float4*)(xrow + (size_t)((c + 2) * 16 + 8 + srow) * 256 + sj * 4);
                if (s == 12) {
                    short4v s4;
                    s4[0] = (short)f2bf(stg.x); s4[1] = (short)f2bf(stg.y);
                    s4[2] = (short)f2bf(stg.z); s4[3] = (short)f2bf(stg.w);
                    *(short4v*)(&xs_wr[(8 + srow) * XP + sj * 4]) = s4;
                }
            }

            // h-matvec in two halves (afh liveness 16 regs, 4 indep chains)
            f32x4 a0lo = {bh[0], 0.f, 0.f, 0.f}, a0hi = {0.f, 0.f, 0.f, 0.f};
            f32x4 a1lo = {bh[1], 0.f, 0.f, 0.f}, a1hi = {0.f, 0.f, 0.f, 0.f};
            {
                short8 afh[4];
#pragma unroll
                for (int ks = 0; ks < 4; ++ks)
                    afh[ks] = *(const short8*)(const void*)(&hbuf[pp][ks * 32 + hi * 8]);
#pragma unroll
                for (int ks = 0; ks < 4; ++ks) {
                    a0lo = __builtin_amdgcn_mfma_f32_16x16x32_bf16(afh[ks], wfh[0][ks], a0lo, 0, 0, 0);
                    a1lo = __builtin_amdgcn_mfma_f32_16x16x32_bf16(afh[ks], wfh[1][ks], a1lo, 0, 0, 0);
                }
            }
            {
                short8 afh[4];
#pragma unroll
                for (int ks = 0; ks < 4; ++ks)
                    afh[ks] = *(const short8*)(const void*)(&hbuf[pp][(ks + 4) * 32 + hi * 8]);
#pragma unroll
                for (int ks = 0; ks < 4; ++ks) {
                    a0hi = __builtin_amdgcn_mfma_f32_16x16x32_bf16(afh[ks], wfh[0][ks + 4], a0hi, 0, 0, 0);
                    a1hi = __builtin_amdgcn_mfma_f32_16x16x32_bf16(afh[ks], wfh[1][ks + 4], a1hi, 0, 0, 0);
                }
            }

            // gate drip: 1 MFMA/step
            accg[pp] = __builtin_amdgcn_mfma_f32_16x16x32_bf16(afg, gbf, accg[pp], 0, 0, 0);

            // epilogue: col n_ep owned by hi<2 threads
            float zz = (hi == 0) ? (a0lo[0] + a0hi[0]) : (a1lo[0] + a1hi[0]);
            zz = fminf(fmaxf(zz, -15.f), 15.f);
            float ex = __expf(2.f * zz);
            float th = (ex - 1.f) * __builtin_amdgcn_rcpf(ex + 1.f);
            if (hi < 2) {
                float hn = g * hreg + (1.f - g) * th;
                hreg = hn;
                hbuf[pp ^ 1][n_ep] = f2bf(hn);
                orow[(size_t)t * 256 + n_ep] = hn;
            }

            if (s == 15) {   // finish gates chunk c+1 (bf16 writes)
#pragma unroll
                for (int r = 0; r < 4; ++r) {
                    gs_wr[(hi * 4 + r) * 256 + w * 32 + lo16]      = f2bf(sigm(accg[0][r] + bx[0]));
                    gs_wr[(hi * 4 + r) * 256 + w * 32 + 16 + lo16] = f2bf(sigm(accg[1][r] + bx[1]));
                }
                f32x4 z = {0.f, 0.f, 0.f, 0.f}; accg[0] = z; accg[1] = z;
            }
        }
    }
}

extern "C" void kernel_launch(void* const* d_in, const int* in_sizes, int n_in,
                              void* d_out, int out_size, void* d_ws, size_t ws_size,
                              hipStream_t stream) {
    const float* x   = (const float*)d_in[0];
    const float* Wxw = (const float*)d_in[1];
    const float* Wxb = (const float*)d_in[2];
    const float* Whw = (const float*)d_in[3];
    const float* Whb = (const float*)d_in[4];
    unsigned short* wxbf = (unsigned short*)d_ws;   // 128 KiB bf16 Wx

    cvt_wx<<<dim3(64), dim3(256), 0, stream>>>(Wxw, wxbf);
    mgu_fused<<<dim3(256), dim3(512), 0, stream>>>(x, wxbf, Wxb, Whw, Whb, (float*)d_out);
}